// Round 20
// baseline (751.944 us; speedup 1.0000x reference)
//
#include <hip/hip_runtime.h>
#include <math.h>

#define BATCH 65536
#define KIN   784
#define HD    768
#define FR    8
#define FCAP  16384   // max flagged rows processed (observed nfix ~2-4k)

typedef float f32x4 __attribute__((ext_vector_type(4)));
typedef short s16x8 __attribute__((ext_vector_type(8)));
typedef unsigned int __attribute__((address_space(3))) lds_u32;
typedef const unsigned int __attribute__((address_space(1))) glb_u32;

__device__ __forceinline__ float frelu(float x){ return x > 0.f ? x : 0.f; }

__device__ __forceinline__ unsigned int cvtpk(float a, float b){
    unsigned int r;
    asm("v_cvt_pk_bf16_f32 %0, %1, %2" : "=v"(r) : "v"(a), "v"(b));
    return r;
}
__device__ __forceinline__ unsigned short f2bf(float v){
    unsigned int u = __builtin_bit_cast(unsigned int, v);
    u += 0x7FFFu + ((u >> 16) & 1u);
    return (unsigned short)(u >> 16);
}
__device__ __forceinline__ float bf2f(unsigned short s){
    unsigned int u = ((unsigned int)s) << 16;
    return __builtin_bit_cast(float, u);
}
__device__ __forceinline__ void gload16(const void* g, void* l){
    __builtin_amdgcn_global_load_lds((glb_u32*)g, (lds_u32*)l, 16, 0, 0);
}
__device__ __forceinline__ void sfence(){ __builtin_amdgcn_sched_barrier(0); }

// ---------------------------------------------------------------------------
// x [B,784] fp32 -> xbf [B,800] bf16 (pad zeroed).
// ---------------------------------------------------------------------------
__global__ __launch_bounds__(256)
void cvtX(const float* __restrict__ x, unsigned short* __restrict__ xbf)
{
    int idx = blockIdx.x * 256 + threadIdx.x;
    int row = idx / 100, c = (idx - row * 100) * 8;
    uint4 o = make_uint4(0, 0, 0, 0);
    if (c < KIN) {
        const float* p = x + (size_t)row * KIN + c;
        float4 a = *(const float4*)p;
        float4 b = *(const float4*)(p + 4);
        o.x = cvtpk(a.x, a.y); o.y = cvtpk(a.z, a.w);
        o.z = cvtpk(b.x, b.y); o.w = cvtpk(b.z, b.w);
    }
    *(uint4*)(xbf + (size_t)row * 800 + c) = o;
}

// ---------------------------------------------------------------------------
// feat = relu(hbf*scale + shift) -> fbf (bf16).
// ---------------------------------------------------------------------------
__global__ __launch_bounds__(256)
void featBN(const unsigned short* __restrict__ hbf,
            const float* __restrict__ scale, const float* __restrict__ shift,
            unsigned short* __restrict__ fbf)
{
    int idx = blockIdx.x * 256 + threadIdx.x;
    int row = idx / 96, c = (idx - row * 96) * 8;
    s16x8 hv = *(const s16x8*)(hbf + (size_t)row * HD + c);
    float4 s0 = *(const float4*)(scale + c), s1 = *(const float4*)(scale + c + 4);
    float4 t0 = *(const float4*)(shift + c), t1 = *(const float4*)(shift + c + 4);
    float v[8];
    v[0] = frelu(bf2f((unsigned short)hv[0]) * s0.x + t0.x);
    v[1] = frelu(bf2f((unsigned short)hv[1]) * s0.y + t0.y);
    v[2] = frelu(bf2f((unsigned short)hv[2]) * s0.z + t0.z);
    v[3] = frelu(bf2f((unsigned short)hv[3]) * s0.w + t0.w);
    v[4] = frelu(bf2f((unsigned short)hv[4]) * s1.x + t1.x);
    v[5] = frelu(bf2f((unsigned short)hv[5]) * s1.y + t1.y);
    v[6] = frelu(bf2f((unsigned short)hv[6]) * s1.z + t1.z);
    v[7] = frelu(bf2f((unsigned short)hv[7]) * s1.w + t1.w);
    uint4 o;
    o.x = cvtpk(v[0], v[1]); o.y = cvtpk(v[2], v[3]);
    o.z = cvtpk(v[4], v[5]); o.w = cvtpk(v[6], v[7]);
    *(uint4*)(fbf + (size_t)row * HD + c) = o;
}

// ---------------------------------------------------------------------------
// Pre-tile W[K][N] fp32 -> bf16 swizzled 8KB chunks (128-col tiles).
// ---------------------------------------------------------------------------
__global__ __launch_bounds__(256)
void tileW(const float* __restrict__ W, char* __restrict__ Wh, int K, int N, int NT)
{
    int chunk = blockIdx.x;
    int nb = chunk / NT, t = chunk - nb * NT;
    int tid = threadIdx.x;
    #pragma unroll
    for (int q = 0; q < 2; q++) {
        int idx = q * 256 + tid;
        int r = idx >> 2, p = idx & 3;
        int s = (p ^ ((r >> 1) & 3)) & 3;
        int kb = t * 32 + s * 8;
        int n = nb * 128 + r;
        s16x8 hv;
        #pragma unroll
        for (int e = 0; e < 8; e++) {
            int k = kb + e;
            float v = (k < K) ? W[(size_t)k * N + n] : 0.f;
            hv[e] = (short)f2bf(v);
        }
        *(s16x8*)(Wh + (size_t)chunk * 8192 + idx * 16) = hv;
    }
}

// ---- Wa[d] 768x64 -> 24 chunks of 4KB per domain (64-row swizzled image) ---
__global__ __launch_bounds__(256)
void tileWa(const float* __restrict__ Wa, char* __restrict__ WaC)
{
    int chunk = blockIdx.x;            // d*24 + t
    int d = chunk / 24, t = chunk - d * 24;
    int idx = threadIdx.x;
    int r = idx >> 2, p = idx & 3;
    int s = (p ^ ((r >> 1) & 3)) & 3;
    int kb = t * 32 + s * 8;
    s16x8 hv;
    #pragma unroll
    for (int e = 0; e < 8; e++)
        hv[e] = (short)f2bf(Wa[((size_t)d * HD + kb + e) * 64 + r]);
    *(s16x8*)(WaC + (size_t)chunk * 4096 + idx * 16) = hv;
}

// ---------------------------------------------------------------------------
// m97-shaped bf16 GEMM with COUNTED-VMCNT depth-2 pipeline (T4): each thread
// issues exactly 4 global_load_lds per tile; tiles t and t+1 stay in flight.
// Per iter: vmcnt(4) [tile t's loads landed, FIFO] -> raw s_barrier ->
// frag reads + MFMA from buf[t&1] -> raw s_barrier (readers done) ->
// stage tile t+2 into buf[t&1]. vmcnt never drains to 0 in-loop.
// r19's dbuf+__syncthreads was NEUTRAL because syncthreads drains vmcnt(0)
// for the just-issued loads — this removes that drain.
// MODE 0: A=xbf(KP=800); epilogue h(bf16) + fused BN column partials.
// MODE 1: A=fbf(KP=768); epilogue a=relu(acc+bd1); domacc += a @ Wd2.
// ---------------------------------------------------------------------------
template<int MODE>
__global__ __launch_bounds__(256, 3)
void gemm97(const unsigned short* __restrict__ Abf,
            const char* __restrict__ BhC,
            const float* __restrict__ bias,
            unsigned short* __restrict__ Hbf,
            const float* __restrict__ Wd2, double* __restrict__ domacc,
            float* __restrict__ sp1, float* __restrict__ sp2,
            int KP, int NT)
{
    __shared__ __align__(16) char sm[32768];  // A dbuf 2x8KB | B dbuf 2x8KB

    int bid = blockIdx.x;
    int wg = (bid & 7) * 384 + (bid >> 3);
    int mb = wg / 6, nb = wg - mb * 6;
    int m0 = mb << 7, n0 = nb << 7;

    int tid = threadIdx.x;
    int lane = tid & 63, wid = tid >> 6;
    int wr = wid >> 1, wc = wid & 1;
    int l15 = lane & 15, l4 = lane >> 4;

    int aoff[4], boff[4];
    #pragma unroll
    for (int f = 0; f < 4; f++) {
        int ra = wr * 64 + f * 16 + l15;
        aoff[f] = ra * 64 + (((l4 ^ (ra >> 1)) & 3) << 4);
        int rb = wc * 64 + f * 16 + l15;
        boff[f] = rb * 64 + (((l4 ^ (rb >> 1)) & 3) << 4);
    }

    int ar[2], asl[2];
    #pragma unroll
    for (int q = 0; q < 2; q++) {
        int idx = q * 256 + tid;
        int r = idx >> 2, p = idx & 3;
        asl[q] = (p ^ ((r >> 1) & 3)) & 3;
        ar[q] = r;
    }

    f32x4 acc[4][4];
    #pragma unroll
    for (int i = 0; i < 4; i++)
        #pragma unroll
        for (int j = 0; j < 4; j++) acc[i][j] = (f32x4){0.f, 0.f, 0.f, 0.f};

    // stage tile t into buffer par (4 gload16 per thread, fixed count for vmcnt)
    auto stage = [&](int t, int par) {
        int pb = par << 13;
        #pragma unroll
        for (int q = 0; q < 2; q++) {
            const unsigned short* src = Abf + (size_t)(m0 + ar[q]) * KP + t * 32 + asl[q] * 8;
            gload16(src, sm + pb + (q * 256 + tid) * 16);
        }
        size_t cb = (size_t)(nb * NT + t) * 8192;
        #pragma unroll
        for (int q = 0; q < 2; q++) {
            int off = (q * 256 + tid) * 16;
            gload16(BhC + cb + off, sm + 16384 + pb + off);
        }
    };

    stage(0, 0);
    stage(1, 1);
    sfence();

    for (int t = 0; t < NT; t++) {
        if (t + 1 < NT) asm volatile("s_waitcnt vmcnt(4)" ::: "memory");
        else            asm volatile("s_waitcnt vmcnt(0)" ::: "memory");
        __builtin_amdgcn_s_barrier();     // all waves' tile-t loads landed
        sfence();
        const char* ab  = sm + ((t & 1) << 13);
        const char* bb2 = sm + 16384 + ((t & 1) << 13);
        s16x8 fah[4], fbh[4];
        #pragma unroll
        for (int f = 0; f < 4; f++) {
            fah[f] = *(const s16x8*)(ab + aoff[f]);
            fbh[f] = *(const s16x8*)(bb2 + boff[f]);
        }
        #pragma unroll
        for (int i = 0; i < 4; i++)
            #pragma unroll
            for (int j = 0; j < 4; j++)
                acc[i][j] = __builtin_amdgcn_mfma_f32_16x16x32_bf16(fah[i], fbh[j], acc[i][j], 0, 0, 0);
        sfence();
        __builtin_amdgcn_s_barrier();     // all readers of buf[t&1] done
        sfence();
        if (t + 2 < NT) stage(t + 2, t & 1);
        sfence();
    }

    if (MODE == 0) {
        float bc[4];
        #pragma unroll
        for (int f = 0; f < 4; f++) bc[f] = bias[n0 + wc * 64 + f * 16 + l15];
        float cs[4] = {0.f,0.f,0.f,0.f}, cq[4] = {0.f,0.f,0.f,0.f};
        #pragma unroll
        for (int i = 0; i < 4; i++) {
            int rowb = m0 + wr * 64 + i * 16 + l4 * 4;
            #pragma unroll
            for (int j2 = 0; j2 < 4; j2++) {
                unsigned short* hrow = Hbf + (size_t)(rowb + j2) * HD + n0 + wc * 64 + l15;
                #pragma unroll
                for (int f = 0; f < 4; f++) {
                    float v = acc[i][f][j2] + bc[f];
                    hrow[f * 16] = (unsigned short)cvtpk(v, v);
                    cs[f] += v; cq[f] += v * v;
                }
            }
        }
        #pragma unroll
        for (int m = 16; m < 64; m <<= 1)
            #pragma unroll
            for (int f = 0; f < 4; f++) {
                cs[f] += __shfl_xor(cs[f], m, 64);
                cq[f] += __shfl_xor(cq[f], m, 64);
            }
        if (l4 == 0) {
            #pragma unroll
            for (int f = 0; f < 4; f++) {
                int col = n0 + wc * 64 + f * 16 + l15;
                sp1[(size_t)col * 1024 + mb * 2 + wr] = cs[f];
                sp2[(size_t)col * 1024 + mb * 2 + wr] = cq[f];
            }
        }
    } else {
        float bc[4], w2[4][3];
        #pragma unroll
        for (int f = 0; f < 4; f++) {
            int col = n0 + wc * 64 + f * 16 + l15;
            bc[f] = bias[col];
            w2[f][0] = Wd2[col * 3 + 0]; w2[f][1] = Wd2[col * 3 + 1]; w2[f][2] = Wd2[col * 3 + 2];
        }
        float s0[16], s1[16], s2[16];
        #pragma unroll
        for (int i = 0; i < 16; i++) { s0[i] = 0.f; s1[i] = 0.f; s2[i] = 0.f; }
        #pragma unroll
        for (int i = 0; i < 4; i++)
            #pragma unroll
            for (int j2 = 0; j2 < 4; j2++) {
                int idx = i * 4 + j2;
                #pragma unroll
                for (int f = 0; f < 4; f++) {
                    float v = frelu(acc[i][f][j2] + bc[f]);
                    s0[idx] += v * w2[f][0];
                    s1[idx] += v * w2[f][1];
                    s2[idx] += v * w2[f][2];
                }
            }
        #pragma unroll
        for (int m = 1; m < 16; m <<= 1) {
            #pragma unroll
            for (int i = 0; i < 16; i++) {
                s0[i] += __shfl_xor(s0[i], m, 64);
                s1[i] += __shfl_xor(s1[i], m, 64);
                s2[i] += __shfl_xor(s2[i], m, 64);
            }
        }
        if (l15 == 0) {
            #pragma unroll
            for (int i = 0; i < 16; i++) {
                int row = m0 + wr * 64 + (i >> 2) * 16 + l4 * 4 + (i & 3);
                atomicAdd(&domacc[(size_t)row * 3 + 0], (double)s0[i]);
                atomicAdd(&domacc[(size_t)row * 3 + 1], (double)s1[i]);
                atomicAdd(&domacc[(size_t)row * 3 + 2], (double)s2[i]);
            }
        }
    }
}

// ---- BN final: reduce 1024 fp32 partials per column in fp64 ----------------
__global__ __launch_bounds__(256)
void bnfinal(const float* __restrict__ sp1, const float* __restrict__ sp2,
             const float* __restrict__ gamma, const float* __restrict__ beta,
             float* __restrict__ scale, float* __restrict__ shift)
{
    int c = blockIdx.x, t = threadIdx.x;
    const float* p1 = sp1 + (size_t)c * 1024;
    const float* p2 = sp2 + (size_t)c * 1024;
    double S = (double)p1[t] + (double)p1[t + 256] + (double)p1[t + 512] + (double)p1[t + 768];
    double Q = (double)p2[t] + (double)p2[t + 256] + (double)p2[t + 512] + (double)p2[t + 768];
    #pragma unroll
    for (int m = 1; m < 64; m <<= 1) { S += __shfl_xor(S, m, 64); Q += __shfl_xor(Q, m, 64); }
    __shared__ double sd1[4], sd2[4];
    int w = t >> 6;
    if ((t & 63) == 0) { sd1[w] = S; sd2[w] = Q; }
    __syncthreads();
    if (t == 0) {
        double Sa = sd1[0] + sd1[1] + sd1[2] + sd1[3];
        double Qa = sd2[0] + sd2[1] + sd2[2] + sd2[3];
        double mu  = Sa * (1.0 / 65536.0);
        double var = Qa * (1.0 / 65536.0) - mu * mu;
        double inv = 1.0 / sqrt(var + 1e-5);
        double sc  = inv * (double)gamma[c];
        double sh  = (double)beta[c] - mu * sc;
        scale[c] = (float)sc;
        shift[c] = (float)sh;
    }
}

// ---- dom_out finalize pass A: write outdom, flag borderline rows -----------
__global__ __launch_bounds__(256)
void domfinal_a(const double* __restrict__ domacc, const float* __restrict__ bd2,
                float* __restrict__ outdom, int* __restrict__ fixmeta, int* __restrict__ fixlist)
{
    int r = blockIdx.x * 256 + threadIdx.x;
    double v0 = domacc[(size_t)r * 3 + 0] + (double)bd2[0];
    double v1 = domacc[(size_t)r * 3 + 1] + (double)bd2[1];
    double v2 = domacc[(size_t)r * 3 + 2] + (double)bd2[2];
    outdom[(size_t)r * 3 + 0] = (float)v0;
    outdom[(size_t)r * 3 + 1] = (float)v1;
    outdom[(size_t)r * 3 + 2] = (float)v2;
    double mx01 = v0 > v1 ? v0 : v1, mn01 = v0 > v1 ? v1 : v0;
    double best = mx01 > v2 ? mx01 : v2;
    double m2   = mx01 > v2 ? (mn01 > v2 ? mn01 : v2) : mx01;
    if (best - m2 < 1.5e-2) {
        int p = atomicAdd(fixmeta, 1);
        fixlist[p] = r;
    }
}

// ---------------------------------------------------------------------------
// fixrow split across BLOCKS (unchanged from r18).
// ---------------------------------------------------------------------------
__global__ __launch_bounds__(256)
void fx_s1(const int* __restrict__ fixmeta, const int* __restrict__ fixlist,
           const float* __restrict__ x, const float* __restrict__ W1,
           float* __restrict__ hfix)
{
    int nfix = fixmeta[0]; if (nfix > FCAP) nfix = FCAP;
    __shared__ float xs[FR][200];
    int tid = threadIdx.x;
    int n0 = tid * 3;
    int p = blockIdx.x & 3, k0 = p * 196;
    int cstep = (gridDim.x >> 2) * FR;
    for (int base = (blockIdx.x >> 2) * FR; base < nfix; base += cstep) {
        int nr = nfix - base; if (nr > FR) nr = FR;
        __syncthreads();
        for (int i = tid; i < FR * 196; i += 256) {
            int rr = i / 196, cc = i - rr * 196;
            int row = fixlist[base + (rr < nr ? rr : nr - 1)];
            xs[rr][cc] = x[(size_t)row * KIN + k0 + cc];
        }
        __syncthreads();
        float acc[FR][3];
        #pragma unroll
        for (int r = 0; r < FR; r++) { acc[r][0]=0.f; acc[r][1]=0.f; acc[r][2]=0.f; }
        for (int kk = 0; kk < 196; kk++) {
            int k = k0 + kk;
            float w0 = W1[(size_t)k * HD + n0];
            float w1 = W1[(size_t)k * HD + n0 + 1];
            float w2 = W1[(size_t)k * HD + n0 + 2];
            #pragma unroll
            for (int r = 0; r < FR; r++) {
                float xv = xs[r][kk];
                acc[r][0] += xv * w0; acc[r][1] += xv * w1; acc[r][2] += xv * w2;
            }
        }
        for (int r = 0; r < nr; r++) {
            atomicAdd(&hfix[(size_t)(base + r) * HD + n0],     acc[r][0]);
            atomicAdd(&hfix[(size_t)(base + r) * HD + n0 + 1], acc[r][1]);
            atomicAdd(&hfix[(size_t)(base + r) * HD + n0 + 2], acc[r][2]);
        }
    }
}

__global__ __launch_bounds__(256)
void fx_s2(const int* __restrict__ fixmeta,
           const float* __restrict__ hfix,
           const float* __restrict__ b1, const float* __restrict__ scale,
           const float* __restrict__ shift,
           const float* __restrict__ Wd1, float* __restrict__ h2fix)
{
    int nfix = fixmeta[0]; if (nfix > FCAP) nfix = FCAP;
    __shared__ float ft[FR][196];
    int tid = threadIdx.x;
    int n0 = tid * 3;
    int p = blockIdx.x & 3, k0 = p * 192;
    int cstep = (gridDim.x >> 2) * FR;
    for (int base = (blockIdx.x >> 2) * FR; base < nfix; base += cstep) {
        int nr = nfix - base; if (nr > FR) nr = FR;
        __syncthreads();
        for (int i = tid; i < FR * 192; i += 256) {
            int rr = i / 192, cc = i - rr * 192;
            int k = k0 + cc;
            int fp = base + (rr < nr ? rr : nr - 1);
            ft[rr][cc] = frelu((hfix[(size_t)fp * HD + k] + b1[k]) * scale[k] + shift[k]);
        }
        __syncthreads();
        float acc[FR][3];
        #pragma unroll
        for (int r = 0; r < FR; r++) { acc[r][0]=0.f; acc[r][1]=0.f; acc[r][2]=0.f; }
        for (int kk = 0; kk < 192; kk++) {
            int k = k0 + kk;
            float w0 = Wd1[(size_t)k * HD + n0];
            float w1 = Wd1[(size_t)k * HD + n0 + 1];
            float w2 = Wd1[(size_t)k * HD + n0 + 2];
            #pragma unroll
            for (int r = 0; r < FR; r++) {
                float fv = ft[r][kk];
                acc[r][0] += fv * w0; acc[r][1] += fv * w1; acc[r][2] += fv * w2;
            }
        }
        for (int r = 0; r < nr; r++) {
            atomicAdd(&h2fix[(size_t)(base + r) * HD + n0],     acc[r][0]);
            atomicAdd(&h2fix[(size_t)(base + r) * HD + n0 + 1], acc[r][1]);
            atomicAdd(&h2fix[(size_t)(base + r) * HD + n0 + 2], acc[r][2]);
        }
    }
}

__global__ __launch_bounds__(256)
void fx_fin(const int* __restrict__ fixmeta, const int* __restrict__ fixlist,
            const float* __restrict__ h2fix,
            const float* __restrict__ bd1, const float* __restrict__ Wd2,
            const float* __restrict__ bd2, float* __restrict__ outdom)
{
    int nfix = fixmeta[0]; if (nfix > FCAP) nfix = FCAP;
    int tid = threadIdx.x, lane = tid & 63, wid = tid >> 6;
    for (int fp = blockIdx.x * 4 + wid; fp < nfix; fp += gridDim.x * 4) {
        int kb = lane * 12;
        float y0 = 0.f, y1 = 0.f, y2 = 0.f;
        #pragma unroll
        for (int j = 0; j < 12; j++) {
            int k = kb + j;
            float hh = frelu(h2fix[(size_t)fp * HD + k] + bd1[k]);
            y0 += hh * Wd2[k * 3 + 0];
            y1 += hh * Wd2[k * 3 + 1];
            y2 += hh * Wd2[k * 3 + 2];
        }
        #pragma unroll
        for (int m = 1; m < 64; m <<= 1) {
            y0 += __shfl_xor(y0, m, 64);
            y1 += __shfl_xor(y1, m, 64);
            y2 += __shfl_xor(y2, m, 64);
        }
        if (lane == 0) {
            int row = fixlist[fp];
            outdom[(size_t)row * 3 + 0] = y0 + bd2[0];
            outdom[(size_t)row * 3 + 1] = y1 + bd2[1];
            outdom[(size_t)row * 3 + 2] = y2 + bd2[2];
        }
    }
}

// ---- pass B: argmax + bucket (block-aggregated atomics) --------------------
__global__ __launch_bounds__(256)
void domfinal_b(const float* __restrict__ outdom, int* __restrict__ cnt, int* __restrict__ lists)
{
    __shared__ int lcnt[3], base[3];
    int tid = threadIdx.x;
    if (tid < 3) lcnt[tid] = 0;
    __syncthreads();
    int r = blockIdx.x * 256 + tid;
    float v0 = outdom[(size_t)r * 3 + 0];
    float v1 = outdom[(size_t)r * 3 + 1];
    float v2 = outdom[(size_t)r * 3 + 2];
    int p = 0; float best = v0;
    if (v1 > best) { best = v1; p = 1; }
    if (v2 > best) { best = v2; p = 2; }
    int lpos = atomicAdd(&lcnt[p], 1);
    __syncthreads();
    if (tid < 3) base[tid] = atomicAdd(&cnt[tid], lcnt[tid]);
    __syncthreads();
    lists[(size_t)p * BATCH + base[p] + lpos] = r;
}

// ---- expert via MFMA: 128 gathered rows x 64(E) x K=768 per block ----------
__global__ __launch_bounds__(256)
void expert_mfma(const unsigned short* __restrict__ fbf,
                 const char* __restrict__ WaC,
                 const int* __restrict__ cnt, const int* __restrict__ lists,
                 const float* __restrict__ ba,
                 const float* __restrict__ Wb, const float* __restrict__ bb,
                 float* __restrict__ outs)
{
    __shared__ __align__(16) char sm[12288];
    __shared__ float hid[128][66];
    __shared__ int rowidx[128];

    int d = blockIdx.y;
    int count = cnt[d];
    int start = blockIdx.x * 128;
    if (start >= count) return;
    int nrows = count - start; if (nrows > 128) nrows = 128;

    int tid = threadIdx.x;
    int lane = tid & 63, wid = tid >> 6;
    int l15 = lane & 15, l4 = lane >> 4;

    if (tid < 128) {
        int i = tid < nrows ? tid : nrows - 1;
        rowidx[tid] = lists[(size_t)d * BATCH + start + i];
    }
    __syncthreads();

    int asl[2], arow[2];
    #pragma unroll
    for (int q = 0; q < 2; q++) {
        int idx = q * 256 + tid;
        int r = idx >> 2, p = idx & 3;
        asl[q] = (p ^ ((r >> 1) & 3)) & 3;
        arow[q] = rowidx[r];
    }

    int aoff[2], boff[4];
    #pragma unroll
    for (int i2 = 0; i2 < 2; i2++) {
        int ra = wid * 32 + i2 * 16 + l15;
        aoff[i2] = ra * 64 + (((l4 ^ (ra >> 1)) & 3) << 4);
    }
    #pragma unroll
    for (int f = 0; f < 4; f++) {
        int rb = f * 16 + l15;
        boff[f] = rb * 64 + (((l4 ^ (rb >> 1)) & 3) << 4);
    }

    f32x4 acc[2][4];
    #pragma unroll
    for (int i = 0; i < 2; i++)
        #pragma unroll
        for (int j = 0; j < 4; j++) acc[i][j] = (f32x4){0.f, 0.f, 0.f, 0.f};

    for (int t = 0; t < 24; t++) {
        #pragma unroll
        for (int q = 0; q < 2; q++)
            gload16(fbf + (size_t)arow[q] * HD + t * 32 + asl[q] * 8,
                    sm + (q * 256 + tid) * 16);
        gload16(WaC + (size_t)(d * 24 + t) * 4096 + tid * 16, sm + 8192 + tid * 16);
        __syncthreads();
        s16x8 fa[2], fb[4];
        #pragma unroll
        for (int i2 = 0; i2 < 2; i2++) fa[i2] = *(const s16x8*)(sm + aoff[i2]);
        #pragma unroll
        for (int f = 0; f < 4; f++)    fb[f]  = *(const s16x8*)(sm + 8192 + boff[f]);
        #pragma unroll
        for (int i2 = 0; i2 < 2; i2++)
            #pragma unroll
            for (int f = 0; f < 4; f++)
                acc[i2][f] = __builtin_amdgcn_mfma_f32_16x16x32_bf16(fa[i2], fb[f], acc[i2][f], 0, 0, 0);
        __syncthreads();
    }

    #pragma unroll
    for (int i2 = 0; i2 < 2; i2++)
        #pragma unroll
        for (int f = 0; f < 4; f++) {
            int col = f * 16 + l15;
            float bav = ba[d * 64 + col];
            #pragma unroll
            for (int j = 0; j < 4; j++) {
                int row = wid * 32 + i2 * 16 + l4 * 4 + j;
                hid[row][col] = frelu(acc[i2][f][j] + bav);
            }
        }
    __syncthreads();

    for (int o = tid; o < 1280; o += 256) {
        int r2 = o / 10, c = o - r2 * 10;
        if (r2 < nrows) {
            float s = 0.f;
            #pragma unroll 16
            for (int l = 0; l < 64; l++) s += hid[r2][l] * Wb[((size_t)d * 64 + l) * 10 + c];
            outs[(size_t)rowidx[r2] * 10 + c] = s + bb[d * 10 + c];
        }
    }
}

// ---------------------------------------------------------------------------
extern "C" void kernel_launch(void* const* d_in, const int* in_sizes, int n_in,
                              void* d_out, int out_size, void* d_ws, size_t ws_size,
                              hipStream_t stream)
{
    const float* x     = (const float*)d_in[0];
    const float* W1    = (const float*)d_in[1];
    const float* b1    = (const float*)d_in[2];
    const float* gamma = (const float*)d_in[3];
    const float* beta  = (const float*)d_in[4];
    const float* Wd1   = (const float*)d_in[5];
    const float* bd1   = (const float*)d_in[6];
    const float* Wd2   = (const float*)d_in[7];
    const float* bd2   = (const float*)d_in[8];
    const float* Wa    = (const float*)d_in[9];
    const float* ba    = (const float*)d_in[10];
    const float* Wb    = (const float*)d_in[11];
    const float* bb    = (const float*)d_in[12];

    float* out    = (float*)d_out;
    float* outs   = out;
    float* outdom = out + (size_t)BATCH * 10;

    const int NT1 = 25, NT2 = 24;

    char* ws = (char*)d_ws;
    size_t off = 0;
    unsigned short* hbf = (unsigned short*)(ws + off); off += (size_t)BATCH * HD * 2;
    unsigned short* xbf = (unsigned short*)(ws + off); off += (size_t)BATCH * 800 * 2;
    unsigned short* fbf = xbf;   // alias: xbf dead after GEMM1
    float* hfix  = (float*)hbf;  // hbf dead after featBN; exactly 2*FCAP*768*4B
    float* h2fix = hfix + (size_t)FCAP * HD;
    char*  W1hC   = ws + off;            off += (size_t)6 * NT1 * 8192;
    char*  Wd1hC  = ws + off;            off += (size_t)6 * NT2 * 8192;
    char*  WaC    = ws + off;            off += (size_t)3 * 24 * 4096;
    float* sp1    = (float*)(ws + off);  off += (size_t)HD * 1024 * 4;
    float* sp2    = (float*)(ws + off);  off += (size_t)HD * 1024 * 4;
    float* scale  = (float*)(ws + off);  off += HD * 4;
    float* shift  = (float*)(ws + off);  off += HD * 4;
    size_t zoff = off;
    double* domacc = (double*)(ws + off); off += (size_t)BATCH * 3 * 8;
    int*    cnt    = (int*)(ws + off);    off += 64;
    int*    fixmeta= (int*)(ws + off);    off += 64;
    size_t zbytes = off - zoff;
    int*    lists  = (int*)(ws + off);    off += (size_t)3 * BATCH * 4;
    int*    fixlist= (int*)(ws + off);    off += (size_t)BATCH * 4;

    hipMemsetAsync(ws + zoff, 0, zbytes, stream);

    tileW<<<6 * NT1, 256, 0, stream>>>(W1, W1hC, KIN, HD, NT1);
    tileW<<<6 * NT2, 256, 0, stream>>>(Wd1, Wd1hC, HD, HD, NT2);
    tileWa<<<72, 256, 0, stream>>>(Wa, WaC);
    cvtX<<<BATCH * 100 / 256, 256, 0, stream>>>(x, xbf);

    gemm97<0><<<3072, 256, 0, stream>>>(xbf, W1hC, b1, hbf,
                                        nullptr, nullptr, sp1, sp2, 800, NT1);
    bnfinal<<<HD, 256, 0, stream>>>(sp1, sp2, gamma, beta, scale, shift);
    featBN<<<BATCH * 96 / 256, 256, 0, stream>>>(hbf, scale, shift, fbf);
    hipMemsetAsync(hfix, 0, (size_t)2 * FCAP * HD * 4, stream);
    gemm97<1><<<3072, 256, 0, stream>>>(fbf, Wd1hC, bd1, nullptr,
                                        Wd2, domacc, nullptr, nullptr, HD, NT2);
    domfinal_a<<<BATCH / 256, 256, 0, stream>>>(domacc, bd2, outdom, fixmeta, fixlist);
    fx_s1<<<8192, 256, 0, stream>>>(fixmeta, fixlist, x, W1, hfix);
    fx_s2<<<8192, 256, 0, stream>>>(fixmeta, hfix, b1, scale, shift, Wd1, h2fix);
    fx_fin<<<512, 256, 0, stream>>>(fixmeta, fixlist, h2fix, bd1, Wd2, bd2, outdom);
    domfinal_b<<<BATCH / 256, 256, 0, stream>>>(outdom, cnt, lists);
    dim3 eg(512, 3);
    expert_mfma<<<eg, 256, 0, stream>>>(fbf, WaC, cnt, lists, ba, Wb, bb, outs);
}